// Round 9
// baseline (164.089 us; speedup 1.0000x reference)
//
#include <hip/hip_runtime.h>

typedef _Float16 half_t;
typedef half_t half2_t __attribute__((ext_vector_type(2)));
typedef half_t half8  __attribute__((ext_vector_type(8)));
typedef unsigned int uint_t;
typedef uint_t uint4v __attribute__((ext_vector_type(4)));
typedef float float4v __attribute__((ext_vector_type(4)));

#define B_  64
#define T_  256
#define F_  16
#define H_  128
#define LOG2E 1.44269504f

__device__ __forceinline__ float rcp_(float x)  { return __builtin_amdgcn_rcpf(x); }
__device__ __forceinline__ float sigm2(float x) { return rcp_(1.0f + __builtin_amdgcn_exp2f(x * -LOG2E)); }
__device__ __forceinline__ float tanh2(float x) { return fmaf(rcp_(1.0f + __builtin_amdgcn_exp2f(x * (-2.0f * LOG2E))), 2.0f, -1.0f); }
__device__ __forceinline__ float sigm(float x)  { return rcp_(1.0f + __expf(-x)); }

// Kernel 0: rank batches by window length desc (approx-LPT dispatch order).
// tasks[r] = {b, s, e, 0}.
__global__ void make_sched(const int* __restrict__ index, int* __restrict__ tasks) {
    __shared__ int ln[B_];
    const int t = threadIdx.x;                 // 64
    const int s = index[2 * t], e = index[2 * t + 1];
    ln[t] = e - s;
    __syncthreads();
    int L = ln[t], r = 0;
    for (int j = 0; j < B_; ++j) r += (ln[j] > L) || (ln[j] == L && j < t);
    int4 v; v.x = t; v.y = s; v.z = e; v.w = 0;
    ((int4*)tasks)[r] = v;
}

// Kernel 1 (unchanged, verified R7/R8): W_hh [F,4H,H] fp32 -> f16 B-frags for
// mfma_f32_16x16x32_f16. Lane `lane` of tile wv8, frag q=m*4+kt, dword e2 holds the
// f16 pair for k = kt*32 + (lane>>4)*8 + 2*e2 (+1), col g = 128*m + 16*wv8 + (lane&15).
__global__ void repack_w(const float* __restrict__ whh, uint_t* __restrict__ wt) {
    const int f = blockIdx.x, w = blockIdx.y, tid = threadIdx.x;  // 256 threads
    const int lane = tid & 63, q4 = tid >> 6;
    const int li = lane & 15, lg = lane >> 4;
    const float* base = whh + (size_t)f * 512 * 128;
#pragma unroll
    for (int qq = 0; qq < 4; ++qq) {
        const int qf = q4 * 4 + qq;
        const int m = qf >> 2, kt = qf & 3;
        const int g512 = 128 * m + 16 * w + li;
        uint_t tmp[4];
#pragma unroll
        for (int e2 = 0; e2 < 4; ++e2) {
            int k = kt * 32 + lg * 8 + 2 * e2;
            half2_t h;
            h[0] = (half_t)base[g512 * 128 + k];
            h[1] = (half_t)base[g512 * 128 + k + 1];
            tmp[e2] = __builtin_bit_cast(uint_t, h);
        }
        uint4 out = { tmp[0], tmp[1], tmp[2], tmp[3] };
        ((uint4*)wt)[(((size_t)f * 8 + qf) * 16 + qf - qf) * 0 + (((size_t)f * 8 + w) * 16 + qf) * 64 + lane] = out;
    }
}

// Kernel 2: one block per (f, chain), 4 waves x 32 cells. Wave w owns col-tiles
// {2w, 2w+1} (cells 32w..32w+31): 32 weight fragsets (128 dwords) per lane via opaque
// asm loads. A has 1 valid row -> A-frag is a broadcast ds_read_b128 of h[kt*32+lg*8..+7];
// all C rows/comps replicate the row-0 gates. Per step: 4 ds_read_b128 + 32 MFMA
// (8 groups of 2x2-deep split chains) + ~60 VALU + 1 barrier over 4 waves.
__global__ __launch_bounds__(256, 2) void lstm_mfma(
    const float* __restrict__ x, const uint_t* __restrict__ wt,
    const float* __restrict__ wih_g, const float* __restrict__ bias_g,
    const int* __restrict__ tasks, float* __restrict__ hout)
{
    __shared__ float xsh[T_];
    __shared__ alignas(16) half_t hbuf[2][H_];

    const int f = blockIdx.x & 15;
    const int4 tk = ((const int4*)tasks)[blockIdx.x >> 4];
    const int b = tk.x, s = tk.y, e = tk.z;
    const int tid = threadIdx.x, lane = tid & 63, w = tid >> 6;   // w = 0..3
    const int li = lane & 15, lg = lane >> 4;
    const int c0 = 32 * w + li;                                    // tile 2w cell
    const int c1 = c0 + 16;                                        // tile 2w+1 cell

    // ---- opaque weight preload: 32 x global_load_dwordx4 (proven resident R4-R8) ----
    uint4v wr[32];
    {
#pragma unroll
        for (int tt = 0; tt < 2; ++tt) {
            const char* ws = (const char*)wt + ((((size_t)f * 8 + 2 * w + tt) * 16) * 64 + lane) * 16;
#pragma unroll
            for (int q = 0; q < 16; ++q) {
                unsigned long long a = (unsigned long long)(ws + (size_t)q * 1024);
                asm volatile("global_load_dwordx4 %0, %1, off" : "=v"(wr[tt * 16 + q]) : "v"(a));
            }
        }
        asm volatile("s_waitcnt vmcnt(0)");
        __builtin_amdgcn_sched_barrier(0);
    }

    float wih[2][4], bb[2][4];
#pragma unroll
    for (int tt = 0; tt < 2; ++tt)
#pragma unroll
        for (int m = 0; m < 4; ++m) {
            wih[tt][m] = wih_g[f * 512 + 128 * m + c0 + 16 * tt];
            bb[tt][m]  = bias_g[f * 512 + 128 * m + c0 + 16 * tt];
        }

    for (int idx = tid; idx < T_; idx += 256) xsh[idx] = x[((size_t)b * T_ + idx) * F_ + f];
    if (tid < H_) hbuf[0][tid] = (half_t)0.0f;

    float cst[2] = {0.f, 0.f}, hst[2] = {0.f, 0.f};
    int pp = 0;
    __syncthreads();

    for (int t = s; t < e; ++t) {
        // A-frags: 4 broadcast ds_read_b128 of current h
        const half_t* hb = &hbuf[pp][lg * 8];
        half8 a0 = *(const half8*)(hb + 0);
        half8 a1 = *(const half8*)(hb + 32);
        half8 a2 = *(const half8*)(hb + 64);
        half8 a3 = *(const half8*)(hb + 96);
        float xt = xsh[t];

        float gv[2][4];
#pragma unroll
        for (int tt = 0; tt < 2; ++tt)
#pragma unroll
            for (int m = 0; m < 4; ++m) {
                float iv = fmaf(xt, wih[tt][m], bb[tt][m]);
                float4v ca = { iv, iv, iv, iv };
                float4v cb = { 0.f, 0.f, 0.f, 0.f };
                // split 4-deep chain into 2x2-deep (shorter dep path)
                ca = __builtin_amdgcn_mfma_f32_16x16x32_f16(a0, __builtin_bit_cast(half8, wr[tt * 16 + m * 4 + 0]), ca, 0, 0, 0);
                cb = __builtin_amdgcn_mfma_f32_16x16x32_f16(a1, __builtin_bit_cast(half8, wr[tt * 16 + m * 4 + 1]), cb, 0, 0, 0);
                ca = __builtin_amdgcn_mfma_f32_16x16x32_f16(a2, __builtin_bit_cast(half8, wr[tt * 16 + m * 4 + 2]), ca, 0, 0, 0);
                cb = __builtin_amdgcn_mfma_f32_16x16x32_f16(a3, __builtin_bit_cast(half8, wr[tt * 16 + m * 4 + 3]), cb, 0, 0, 0);
                gv[tt][m] = ca[0] + cb[0];   // row 0 replicated into comp 0 of every lane
            }

#pragma unroll
        for (int tt = 0; tt < 2; ++tt) {
            float gi = sigm2(gv[tt][0]);
            float gf = sigm2(gv[tt][1]);
            float gg = tanh2(gv[tt][2]);
            float go = sigm2(gv[tt][3]);
            cst[tt] = fmaf(gf, cst[tt], gi * gg);
            hst[tt] = go * tanh2(cst[tt]);
        }

        if (lg == 0)      hbuf[pp ^ 1][c0] = (half_t)hst[0];
        else if (lg == 1) hbuf[pp ^ 1][c1] = (half_t)hst[1];
        __syncthreads();
        pp ^= 1;
    }

    if (lg == 0) hout[((size_t)b * F_ + f) * H_ + c0] = hst[0];
    if (lg == 1) hout[((size_t)b * F_ + f) * H_ + c1] = hst[1];
}

// Kernel 3: per-batch epilogue: mean over H -> conv3 (pad 1) -> sigmoid gate -> gated fc.
__global__ void epilogue(const float* __restrict__ hout, const float* __restrict__ conv_w,
                         const float* __restrict__ fc_w, const float* __restrict__ fc_b,
                         float* __restrict__ out)
{
    const int b = blockIdx.x, t = threadIdx.x;   // 128 threads
    const int lane = t & 63, wv = t >> 6;
    __shared__ float part[2][16];
    __shared__ float gate_sh[16];

    float hv[16];
#pragma unroll
    for (int f = 0; f < 16; ++f) hv[f] = hout[((size_t)b * 16 + f) * 128 + t];

#pragma unroll
    for (int f = 0; f < 16; ++f) {
        float s = hv[f];
#pragma unroll
        for (int off = 32; off >= 1; off >>= 1) s += __shfl_down(s, off, 64);
        if (lane == 0) part[wv][f] = s;
    }
    __syncthreads();
    if (t < 16) gate_sh[t] = (part[0][t] + part[1][t]) * (1.0f / 128.0f);
    __syncthreads();
    float gate = 0.0f;
    if (t < 16) {
        float l  = (t > 0)  ? gate_sh[t - 1] : 0.0f;
        float mi = gate_sh[t];
        float r  = (t < 15) ? gate_sh[t + 1] : 0.0f;
        gate = sigm(fmaf(l, conv_w[0], fmaf(mi, conv_w[1], r * conv_w[2])));
    }
    __syncthreads();
    if (t < 16) gate_sh[t] = gate;
    __syncthreads();

    float acc0 = 0.0f, acc1 = 0.0f;
    const float2* fw2 = (const float2*)fc_w;
#pragma unroll
    for (int f = 0; f < 16; ++f) {
        float hg = hv[f] * gate_sh[f];
        float2 w2 = fw2[f * 128 + t];
        acc0 = fmaf(hg, w2.x, acc0);
        acc1 = fmaf(hg, w2.y, acc1);
    }
#pragma unroll
    for (int off = 32; off >= 1; off >>= 1) {
        acc0 += __shfl_down(acc0, off, 64);
        acc1 += __shfl_down(acc1, off, 64);
    }
    if (lane == 0) { part[wv][0] = acc0; part[wv][1] = acc1; }
    __syncthreads();
    if (t == 0) {
        out[b * 2 + 0] = part[0][0] + part[1][0] + fc_b[0];
        out[b * 2 + 1] = part[0][1] + part[1][1] + fc_b[1];
    }
}

extern "C" void kernel_launch(void* const* d_in, const int* in_sizes, int n_in,
                              void* d_out, int out_size, void* d_ws, size_t ws_size,
                              hipStream_t stream) {
    const float* x      = (const float*)d_in[0];
    const int*   index  = (const int*)  d_in[1];
    const float* W_ih   = (const float*)d_in[2];
    const float* W_hh   = (const float*)d_in[3];
    const float* bias   = (const float*)d_in[4];
    const float* conv_w = (const float*)d_in[5];
    const float* fc_w   = (const float*)d_in[6];
    const float* fc_b   = (const float*)d_in[7];
    float* out = (float*)d_out;

    uint_t* wt    = (uint_t*)d_ws;                                     // 2 MB
    float*  hout  = (float*)((char*)d_ws + 2 * 1024 * 1024);           // 512 KB
    int*    tasks = (int*)((char*)d_ws + 2 * 1024 * 1024 + 512 * 1024); // 1 KB

    make_sched<<<1, 64, 0, stream>>>(index, tasks);
    repack_w<<<dim3(F_, 8), 256, 0, stream>>>(W_hh, wt);
    lstm_mfma<<<1024, 256, 0, stream>>>(x, wt, W_ih, bias, tasks, hout);
    epilogue<<<B_, 128, 0, stream>>>(hout, conv_w, fc_w, fc_b, out);
}

// Round 10
// 146.483 us; speedup vs baseline: 1.1202x; 1.1202x over previous
//
#include <hip/hip_runtime.h>

typedef _Float16 half_t;
typedef half_t half2_t __attribute__((ext_vector_type(2)));
typedef half_t half8  __attribute__((ext_vector_type(8)));
typedef unsigned int uint_t;
typedef uint_t uint4v __attribute__((ext_vector_type(4)));
typedef float float4v __attribute__((ext_vector_type(4)));

#define B_  64
#define T_  256
#define F_  16
#define H_  128
#define LOG2E 1.44269504f

__device__ __forceinline__ float rcp_(float x)  { return __builtin_amdgcn_rcpf(x); }
__device__ __forceinline__ float sigm2(float x) { return rcp_(1.0f + __builtin_amdgcn_exp2f(x * -LOG2E)); }
__device__ __forceinline__ float tanh2(float x) { return fmaf(rcp_(1.0f + __builtin_amdgcn_exp2f(x * (-2.0f * LOG2E))), 2.0f, -1.0f); }
__device__ __forceinline__ float sigm(float x)  { return rcp_(1.0f + __expf(-x)); }

// Kernel 0: rank batches by window midpoint; pair consecutive ranks (similar windows
// -> union ~ max not sum). pairs[p] = {bA<<8|bB, sA<<16|eA, sB<<16|eB, su<<16|eu}.
__global__ void make_sched(const int* __restrict__ index, int* __restrict__ pairs) {
    __shared__ int ss[B_], ee[B_], mid[B_], bo[B_];
    const int t = threadIdx.x;                 // 64
    const int s = index[2 * t], e = index[2 * t + 1];
    ss[t] = s; ee[t] = e; mid[t] = s + e;
    __syncthreads();
    int m = mid[t], r = 0;
    for (int j = 0; j < B_; ++j) r += (mid[j] < m) || (mid[j] == m && j < t);
    bo[r] = t;
    __syncthreads();
    if (t < 32) {
        int bA = bo[2 * t], bB = bo[2 * t + 1];
        int su = min(ss[bA], ss[bB]), eu = max(ee[bA], ee[bB]);
        int4 v;
        v.x = (bA << 8) | bB;
        v.y = (ss[bA] << 16) | ee[bA];
        v.z = (ss[bB] << 16) | ee[bB];
        v.w = (su << 16) | eu;
        ((int4*)pairs)[t] = v;
    }
}

// Kernel 1 (verified R7/R8): W_hh [F,4H,H] fp32 -> f16 B-frags for mfma_f32_16x16x32_f16.
// Lane `lane` of tile w8, frag q=m*4+kt, dword e2 holds the f16 pair for
// k = kt*32 + (lane>>4)*8 + 2*e2 (+1), col g = 128*m + 16*w8 + (lane&15).
__global__ void repack_w(const float* __restrict__ whh, uint_t* __restrict__ wt) {
    const int f = blockIdx.x, w = blockIdx.y, tid = threadIdx.x;  // 256 threads
    const int lane = tid & 63, q4 = tid >> 6;
    const int li = lane & 15, lg = lane >> 4;
    const float* base = whh + (size_t)f * 512 * 128;
#pragma unroll
    for (int qq = 0; qq < 4; ++qq) {
        const int qf = q4 * 4 + qq;
        const int m = qf >> 2, kt = qf & 3;
        const int g512 = 128 * m + 16 * w + li;
        uint_t tmp[4];
#pragma unroll
        for (int e2 = 0; e2 < 4; ++e2) {
            int k = kt * 32 + lg * 8 + 2 * e2;
            half2_t h;
            h[0] = (half_t)base[g512 * 128 + k];
            h[1] = (half_t)base[g512 * 128 + k + 1];
            tmp[e2] = __builtin_bit_cast(uint_t, h);
        }
        uint4 out = { tmp[0], tmp[1], tmp[2], tmp[3] };
        ((uint4*)wt)[(((size_t)f * 8 + w) * 16 + qf) * 64 + lane] = out;
    }
}

// Kernel 2: one block per (f, chain-PAIR); 8 waves (R8 structure). A rows 0-7 carry
// batch-A's h, rows 8-15 batch-B's (lane's A-row = li -> li<8 reads bufA, li>=8 bufB;
// 2-way broadcast = free). C rows 0-7 = A gates, 8-15 = B gates -> lane (li,lg) owns
// cell 16w+li of batch (lg>=2), reg 0. Same 128 MFMA/step now serve TWO chains.
// 512 blocks x 512 thr = 2 blocks/CU, all co-resident -> makespan ~ max pair-union.
__global__ __launch_bounds__(512, 4) void lstm_mfma(
    const float* __restrict__ x, const uint_t* __restrict__ wt,
    const float* __restrict__ wih_g, const float* __restrict__ bias_g,
    const int* __restrict__ pairs, float* __restrict__ hout)
{
    __shared__ float xsh[2][T_];
    __shared__ alignas(16) half_t hbuf[2][2][H_];   // [buf][batch][cell]

    const int f = blockIdx.x & 15;
    const int4 pv = ((const int4*)pairs)[blockIdx.x >> 4];
    const int bA = pv.x >> 8, bB = pv.x & 255;
    const int sA = pv.y >> 16, eA = pv.y & 0xffff;
    const int sB = pv.z >> 16, eB = pv.z & 0xffff;
    const int su = pv.w >> 16, eu = pv.w & 0xffff;

    const int tid = threadIdx.x, lane = tid & 63, w = tid >> 6;
    const int li = lane & 15, lg = lane >> 4;
    const int cell = 16 * w + li;
    const int hsel = li >> 3;                 // A-frag row group: 0 -> batch A, 1 -> B
    const int csel = lg >> 1;                 // C row group: 0 -> batch A, 1 -> B

    // ---- opaque weight preload: 16 x global_load_dwordx4 (proven resident R4-R8) ----
    uint4v wr[16];
    {
        const char* ws = (const char*)wt + ((((size_t)f * 8 + w) * 16) * 64 + lane) * 16;
#pragma unroll
        for (int q = 0; q < 16; ++q) {
            unsigned long long a = (unsigned long long)(ws + (size_t)q * 1024);
            asm volatile("global_load_dwordx4 %0, %1, off" : "=v"(wr[q]) : "v"(a));
        }
        asm volatile("s_waitcnt vmcnt(0)");
        __builtin_amdgcn_sched_barrier(0);
    }

    float wih[4], bb4[4];
#pragma unroll
    for (int m = 0; m < 4; ++m) {
        wih[m] = wih_g[f * 512 + 128 * m + cell];
        bb4[m] = bias_g[f * 512 + 128 * m + cell];
    }

    const int myb = csel ? bB : bA;
    const int mys = csel ? sB : sA;
    const int mye = csel ? eB : eA;

    // stage x rows for both batches; zero h buffer 0 (both batches)
    {
        int bb_ = tid >> 8, tt = tid & 255;
        xsh[bb_][tt] = x[((size_t)(bb_ ? bB : bA) * T_ + tt) * F_ + f];
    }
    if (tid < 2 * H_) hbuf[0][tid >> 7][tid & 127] = (half_t)0.0f;

    float cst = 0.0f, hst = 0.0f;
    int pp = 0;
    __syncthreads();

    for (int t = su; t < eu; ++t) {
        // A-frags: broadcast reads of current h for this lane's A-row batch
        const half_t* hb = &hbuf[pp][hsel][lg * 8];
        half8 a0 = *(const half8*)(hb + 0);
        half8 a1 = *(const half8*)(hb + 32);
        half8 a2 = *(const half8*)(hb + 64);
        half8 a3 = *(const half8*)(hb + 96);
        float xt = xsh[csel][t];

        float gv[4];
#pragma unroll
        for (int m = 0; m < 4; ++m) {
            float iv = fmaf(xt, wih[m], bb4[m]);
            float4v ca = { iv, iv, iv, iv };
            float4v cb = { 0.f, 0.f, 0.f, 0.f };
            ca = __builtin_amdgcn_mfma_f32_16x16x32_f16(a0, __builtin_bit_cast(half8, wr[m * 4 + 0]), ca, 0, 0, 0);
            cb = __builtin_amdgcn_mfma_f32_16x16x32_f16(a1, __builtin_bit_cast(half8, wr[m * 4 + 1]), cb, 0, 0, 0);
            ca = __builtin_amdgcn_mfma_f32_16x16x32_f16(a2, __builtin_bit_cast(half8, wr[m * 4 + 2]), ca, 0, 0, 0);
            cb = __builtin_amdgcn_mfma_f32_16x16x32_f16(a3, __builtin_bit_cast(half8, wr[m * 4 + 3]), cb, 0, 0, 0);
            gv[m] = ca[0] + cb[0];   // reg 0: row lg*4 -> batch (lg>=2), replicated
        }

        float gi = sigm2(gv[0]);
        float gf = sigm2(gv[1]);
        float gg = tanh2(gv[2]);
        float go = sigm2(gv[3]);
        float cn = fmaf(gf, cst, gi * gg);
        bool mk = (t >= mys) & (t < mye);
        cst = mk ? cn : cst;
        float hn = go * tanh2(cst);
        hst = mk ? hn : hst;

        if (lg == 0)      hbuf[pp ^ 1][0][cell] = (half_t)hst;
        else if (lg == 2) hbuf[pp ^ 1][1][cell] = (half_t)hst;
        __syncthreads();
        pp ^= 1;
    }

    if ((lg & 1) == 0) hout[((size_t)myb * F_ + f) * H_ + cell] = hst;
}

// Kernel 3: per-batch epilogue: mean over H -> conv3 (pad 1) -> sigmoid gate -> gated fc.
__global__ void epilogue(const float* __restrict__ hout, const float* __restrict__ conv_w,
                         const float* __restrict__ fc_w, const float* __restrict__ fc_b,
                         float* __restrict__ out)
{
    const int b = blockIdx.x, t = threadIdx.x;   // 128 threads
    const int lane = t & 63, wv = t >> 6;
    __shared__ float part[2][16];
    __shared__ float gate_sh[16];

    float hv[16];
#pragma unroll
    for (int f = 0; f < 16; ++f) hv[f] = hout[((size_t)b * 16 + f) * 128 + t];

#pragma unroll
    for (int f = 0; f < 16; ++f) {
        float s = hv[f];
#pragma unroll
        for (int off = 32; off >= 1; off >>= 1) s += __shfl_down(s, off, 64);
        if (lane == 0) part[wv][f] = s;
    }
    __syncthreads();
    if (t < 16) gate_sh[t] = (part[0][t] + part[1][t]) * (1.0f / 128.0f);
    __syncthreads();
    float gate = 0.0f;
    if (t < 16) {
        float l  = (t > 0)  ? gate_sh[t - 1] : 0.0f;
        float mi = gate_sh[t];
        float r  = (t < 15) ? gate_sh[t + 1] : 0.0f;
        gate = sigm(fmaf(l, conv_w[0], fmaf(mi, conv_w[1], r * conv_w[2])));
    }
    __syncthreads();
    if (t < 16) gate_sh[t] = gate;
    __syncthreads();

    float acc0 = 0.0f, acc1 = 0.0f;
    const float2* fw2 = (const float2*)fc_w;
#pragma unroll
    for (int f = 0; f < 16; ++f) {
        float hg = hv[f] * gate_sh[f];
        float2 w2 = fw2[f * 128 + t];
        acc0 = fmaf(hg, w2.x, acc0);
        acc1 = fmaf(hg, w2.y, acc1);
    }
#pragma unroll
    for (int off = 32; off >= 1; off >>= 1) {
        acc0 += __shfl_down(acc0, off, 64);
        acc1 += __shfl_down(acc1, off, 64);
    }
    if (lane == 0) { part[wv][0] = acc0; part[wv][1] = acc1; }
    __syncthreads();
    if (t == 0) {
        out[b * 2 + 0] = part[0][0] + part[1][0] + fc_b[0];
        out[b * 2 + 1] = part[0][1] + part[1][1] + fc_b[1];
    }
}

extern "C" void kernel_launch(void* const* d_in, const int* in_sizes, int n_in,
                              void* d_out, int out_size, void* d_ws, size_t ws_size,
                              hipStream_t stream) {
    const float* x      = (const float*)d_in[0];
    const int*   index  = (const int*)  d_in[1];
    const float* W_ih   = (const float*)d_in[2];
    const float* W_hh   = (const float*)d_in[3];
    const float* bias   = (const float*)d_in[4];
    const float* conv_w = (const float*)d_in[5];
    const float* fc_w   = (const float*)d_in[6];
    const float* fc_b   = (const float*)d_in[7];
    float* out = (float*)d_out;

    uint_t* wt    = (uint_t*)d_ws;                                     // 2 MB
    float*  hout  = (float*)((char*)d_ws + 2 * 1024 * 1024);           // 512 KB
    int*    pairs = (int*)((char*)d_ws + 2 * 1024 * 1024 + 512 * 1024); // 512 B

    make_sched<<<1, 64, 0, stream>>>(index, pairs);
    repack_w<<<dim3(F_, 8), 256, 0, stream>>>(W_hh, wt);
    lstm_mfma<<<512, 512, 0, stream>>>(x, wt, W_ih, bias, pairs, hout);
    epilogue<<<B_, 128, 0, stream>>>(hout, conv_w, fc_w, fc_b, out);
}

// Round 11
// 136.048 us; speedup vs baseline: 1.2061x; 1.0767x over previous
//
#include <hip/hip_runtime.h>

typedef _Float16 half_t;
typedef half_t half2_t __attribute__((ext_vector_type(2)));
typedef half_t half8  __attribute__((ext_vector_type(8)));
typedef unsigned int uint_t;
typedef uint_t uint4v __attribute__((ext_vector_type(4)));
typedef float float4v __attribute__((ext_vector_type(4)));

#define B_  64
#define T_  256
#define F_  16
#define H_  128
#define HP  160   // padded batch stride (320 B) -> bufB reads land on banks 16-31
#define LOG2E 1.44269504f

__device__ __forceinline__ float rcp_(float x)  { return __builtin_amdgcn_rcpf(x); }
__device__ __forceinline__ float sigm2(float x) { return rcp_(1.0f + __builtin_amdgcn_exp2f(x * -LOG2E)); }
__device__ __forceinline__ float tanh2(float x) { return fmaf(rcp_(1.0f + __builtin_amdgcn_exp2f(x * (-2.0f * LOG2E))), 2.0f, -1.0f); }
__device__ __forceinline__ float sigm(float x)  { return rcp_(1.0f + __expf(-x)); }

// Kernel 0: rank batches by window midpoint; pair consecutive ranks (similar windows
// -> union ~ max not sum). pairs[p] = {bA<<8|bB, sA<<16|eA, sB<<16|eB, su<<16|eu}.
__global__ void make_sched(const int* __restrict__ index, int* __restrict__ pairs) {
    __shared__ int ss[B_], ee[B_], mid[B_], bo[B_];
    const int t = threadIdx.x;                 // 64
    const int s = index[2 * t], e = index[2 * t + 1];
    ss[t] = s; ee[t] = e; mid[t] = s + e;
    __syncthreads();
    int m = mid[t], r = 0;
    for (int j = 0; j < B_; ++j) r += (mid[j] < m) || (mid[j] == m && j < t);
    bo[r] = t;
    __syncthreads();
    if (t < 32) {
        int bA = bo[2 * t], bB = bo[2 * t + 1];
        int su = min(ss[bA], ss[bB]), eu = max(ee[bA], ee[bB]);
        int4 v;
        v.x = (bA << 8) | bB;
        v.y = (ss[bA] << 16) | ee[bA];
        v.z = (ss[bB] << 16) | ee[bB];
        v.w = (su << 16) | eu;
        ((int4*)pairs)[t] = v;
    }
}

// Kernel 1 (verified R7-R10): W_hh [F,4H,H] fp32 -> f16 B-frags for mfma_f32_16x16x32_f16.
// Lane `lane` of tile w8, frag q=m*4+kt, dword e2 holds the f16 pair for
// k = kt*32 + (lane>>4)*8 + 2*e2 (+1), col g = 128*m + 16*w8 + (lane&15).
__global__ void repack_w(const float* __restrict__ whh, uint_t* __restrict__ wt) {
    const int f = blockIdx.x, w = blockIdx.y, tid = threadIdx.x;  // 256 threads
    const int lane = tid & 63, q4 = tid >> 6;
    const int li = lane & 15, lg = lane >> 4;
    const float* base = whh + (size_t)f * 512 * 128;
#pragma unroll
    for (int qq = 0; qq < 4; ++qq) {
        const int qf = q4 * 4 + qq;
        const int m = qf >> 2, kt = qf & 3;
        const int g512 = 128 * m + 16 * w + li;
        uint_t tmp[4];
#pragma unroll
        for (int e2 = 0; e2 < 4; ++e2) {
            int k = kt * 32 + lg * 8 + 2 * e2;
            half2_t h;
            h[0] = (half_t)base[g512 * 128 + k];
            h[1] = (half_t)base[g512 * 128 + k + 1];
            tmp[e2] = __builtin_bit_cast(uint_t, h);
        }
        uint4 out = { tmp[0], tmp[1], tmp[2], tmp[3] };
        ((uint4*)wt)[(((size_t)f * 8 + w) * 16 + qf) * 64 + lane] = out;
    }
}

// Kernel 2: one block per (f, chain-PAIR); 8 waves. A rows 0-7 = batch A's h, rows
// 8-15 = batch B's (lane's A-row = li -> li<8 reads bufA, li>=8 bufB). C rows 0-7 =
// A gates, 8-15 = B gates -> lane (li,lg) owns cell 16w+li of batch (lg>=2), reg 0.
// Padded hbuf batch stride (320 B) makes bufA/bufB reads bank-disjoint (R10: 7.5M
// conflict cycles from 256 B stride aliasing banks 0-15).
__global__ __launch_bounds__(512, 4) void lstm_mfma(
    const float* __restrict__ x, const uint_t* __restrict__ wt,
    const float* __restrict__ wih_g, const float* __restrict__ bias_g,
    const int* __restrict__ pairs, float* __restrict__ hout)
{
    __shared__ float xsh[2][T_ + 8];
    __shared__ alignas(16) half_t hbuf[2][2][HP];   // [buf][batch][cell], padded

    const int f = blockIdx.x & 15;
    const int4 pv = ((const int4*)pairs)[blockIdx.x >> 4];
    const int bA = pv.x >> 8, bB = pv.x & 255;
    const int sA = pv.y >> 16, eA = pv.y & 0xffff;
    const int sB = pv.z >> 16, eB = pv.z & 0xffff;
    const int su = pv.w >> 16, eu = pv.w & 0xffff;

    const int tid = threadIdx.x, lane = tid & 63, w = tid >> 6;
    const int li = lane & 15, lg = lane >> 4;
    const int cell = 16 * w + li;
    const int hsel = li >> 3;                 // A-frag row group: 0 -> batch A, 1 -> B
    const int csel = lg >> 1;                 // C row group: 0 -> batch A, 1 -> B

    // ---- opaque weight preload: 16 x global_load_dwordx4 (proven resident R4-R10) ----
    uint4v wr[16];
    {
        const char* ws = (const char*)wt + ((((size_t)f * 8 + w) * 16) * 64 + lane) * 16;
#pragma unroll
        for (int q = 0; q < 16; ++q) {
            unsigned long long a = (unsigned long long)(ws + (size_t)q * 1024);
            asm volatile("global_load_dwordx4 %0, %1, off" : "=v"(wr[q]) : "v"(a));
        }
        asm volatile("s_waitcnt vmcnt(0)");
        __builtin_amdgcn_sched_barrier(0);
    }

    float wih[4], bb4[4];
#pragma unroll
    for (int m = 0; m < 4; ++m) {
        wih[m] = wih_g[f * 512 + 128 * m + cell];
        bb4[m] = bias_g[f * 512 + 128 * m + cell];
    }

    const int myb = csel ? bB : bA;
    const int mys = csel ? sB : sA;
    const int mye = csel ? eB : eA;

    // stage x rows for both batches; zero h buffer 0 (both batches)
    {
        int bb_ = tid >> 8, tt = tid & 255;
        xsh[bb_][tt] = x[((size_t)(bb_ ? bB : bA) * T_ + tt) * F_ + f];
    }
    if (tid < 2 * H_) hbuf[0][tid >> 7][tid & 127] = (half_t)0.0f;

    float cst = 0.0f, hst = 0.0f;
    int pp = 0;
    __syncthreads();

    for (int t = su; t < eu; ++t) {
        // A-frags: broadcast reads of current h for this lane's A-row batch
        const half_t* hb = &hbuf[pp][hsel][lg * 8];
        half8 a0 = *(const half8*)(hb + 0);
        half8 a1 = *(const half8*)(hb + 32);
        half8 a2 = *(const half8*)(hb + 64);
        half8 a3 = *(const half8*)(hb + 96);
        float xt = xsh[csel][t];

        float gv[4];
#pragma unroll
        for (int m = 0; m < 4; ++m) {
            float iv = fmaf(xt, wih[m], bb4[m]);
            float4v ci = { iv, iv, iv, iv };   // single 4-deep chain (issue-bound regime)
            ci = __builtin_amdgcn_mfma_f32_16x16x32_f16(a0, __builtin_bit_cast(half8, wr[m * 4 + 0]), ci, 0, 0, 0);
            ci = __builtin_amdgcn_mfma_f32_16x16x32_f16(a1, __builtin_bit_cast(half8, wr[m * 4 + 1]), ci, 0, 0, 0);
            ci = __builtin_amdgcn_mfma_f32_16x16x32_f16(a2, __builtin_bit_cast(half8, wr[m * 4 + 2]), ci, 0, 0, 0);
            ci = __builtin_amdgcn_mfma_f32_16x16x32_f16(a3, __builtin_bit_cast(half8, wr[m * 4 + 3]), ci, 0, 0, 0);
            gv[m] = ci[0];                     // reg 0: row lg*4 -> this lane's batch
        }

        float gi = sigm2(gv[0]);
        float gf = sigm2(gv[1]);
        float gg = tanh2(gv[2]);
        float go = sigm2(gv[3]);
        float cn = fmaf(gf, cst, gi * gg);
        bool mk = (t >= mys) & (t < mye);
        cst = mk ? cn : cst;
        float hn = go * tanh2(cst);
        hst = mk ? hn : hst;

        if ((lg & 1) == 0) hbuf[pp ^ 1][csel][cell] = (half_t)hst;
        __syncthreads();
        pp ^= 1;
    }

    if ((lg & 1) == 0) hout[((size_t)myb * F_ + f) * H_ + cell] = hst;
}

// Kernel 3: per-batch epilogue: mean over H -> conv3 (pad 1) -> sigmoid gate -> gated fc.
__global__ void epilogue(const float* __restrict__ hout, const float* __restrict__ conv_w,
                         const float* __restrict__ fc_w, const float* __restrict__ fc_b,
                         float* __restrict__ out)
{
    const int b = blockIdx.x, t = threadIdx.x;   // 128 threads
    const int lane = t & 63, wv = t >> 6;
    __shared__ float part[2][16];
    __shared__ float gate_sh[16];

    float hv[16];
#pragma unroll
    for (int f = 0; f < 16; ++f) hv[f] = hout[((size_t)b * 16 + f) * 128 + t];

#pragma unroll
    for (int f = 0; f < 16; ++f) {
        float s = hv[f];
#pragma unroll
        for (int off = 32; off >= 1; off >>= 1) s += __shfl_down(s, off, 64);
        if (lane == 0) part[wv][f] = s;
    }
    __syncthreads();
    if (t < 16) gate_sh[t] = (part[0][t] + part[1][t]) * (1.0f / 128.0f);
    __syncthreads();
    float gate = 0.0f;
    if (t < 16) {
        float l  = (t > 0)  ? gate_sh[t - 1] : 0.0f;
        float mi = gate_sh[t];
        float r  = (t < 15) ? gate_sh[t + 1] : 0.0f;
        gate = sigm(fmaf(l, conv_w[0], fmaf(mi, conv_w[1], r * conv_w[2])));
    }
    __syncthreads();
    if (t < 16) gate_sh[t] = gate;
    __syncthreads();

    float acc0 = 0.0f, acc1 = 0.0f;
    const float2* fw2 = (const float2*)fc_w;
#pragma unroll
    for (int f = 0; f < 16; ++f) {
        float hg = hv[f] * gate_sh[f];
        float2 w2 = fw2[f * 128 + t];
        acc0 = fmaf(hg, w2.x, acc0);
        acc1 = fmaf(hg, w2.y, acc1);
    }
#pragma unroll
    for (int off = 32; off >= 1; off >>= 1) {
        acc0 += __shfl_down(acc0, off, 64);
        acc1 += __shfl_down(acc1, off, 64);
    }
    if (lane == 0) { part[wv][0] = acc0; part[wv][1] = acc1; }
    __syncthreads();
    if (t == 0) {
        out[b * 2 + 0] = part[0][0] + part[1][0] + fc_b[0];
        out[b * 2 + 1] = part[0][1] + part[1][1] + fc_b[1];
    }
}

extern "C" void kernel_launch(void* const* d_in, const int* in_sizes, int n_in,
                              void* d_out, int out_size, void* d_ws, size_t ws_size,
                              hipStream_t stream) {
    const float* x      = (const float*)d_in[0];
    const int*   index  = (const int*)  d_in[1];
    const float* W_ih   = (const float*)d_in[2];
    const float* W_hh   = (const float*)d_in[3];
    const float* bias   = (const float*)d_in[4];
    const float* conv_w = (const float*)d_in[5];
    const float* fc_w   = (const float*)d_in[6];
    const float* fc_b   = (const float*)d_in[7];
    float* out = (float*)d_out;

    uint_t* wt    = (uint_t*)d_ws;                                     // 2 MB
    float*  hout  = (float*)((char*)d_ws + 2 * 1024 * 1024);           // 512 KB
    int*    pairs = (int*)((char*)d_ws + 2 * 1024 * 1024 + 512 * 1024); // 512 B

    make_sched<<<1, 64, 0, stream>>>(index, pairs);
    repack_w<<<dim3(F_, 8), 256, 0, stream>>>(W_hh, wt);
    lstm_mfma<<<512, 512, 0, stream>>>(x, wt, W_ih, bias, pairs, hout);
    epilogue<<<B_, 128, 0, stream>>>(hout, conv_w, fc_w, fc_b, out);
}